// Round 1
// baseline (2668.041 us; speedup 1.0000x reference)
//
#include <hip/hip_runtime.h>

// VectorQuantizer: x [32,256,32,32] f32, codebook [8192,256] f32
// out: quantized [32,256,32,32] f32 (8388608 floats) ++ indices [32768] as f32
#define B_   32
#define C_   256
#define P_   1024     // 32*32 spatial
#define N_   32768    // 32*1024
#define K_   8192
#define TN   64
#define TK   64
#define QOFF 8388608  // offset of indices in d_out (floats)

// ---------------- kernel 1: cb_sq[k] = fl32( sum_c fl32(cb[k][c]^2) ) ----------------
__global__ __launch_bounds__(256) void cbsq_kernel(const float* __restrict__ cb,
                                                   float* __restrict__ cbsq) {
    const int row  = blockIdx.x * 4 + (threadIdx.x >> 6);
    const int lane = threadIdx.x & 63;
    const float4 v = *reinterpret_cast<const float4*>(cb + row * C_ + lane * 4);
    // round products to f32 first (matches np: codebook*codebook then sum)
    float p0 = v.x * v.x, p1 = v.y * v.y, p2 = v.z * v.z, p3 = v.w * v.w;
    double acc = (double)p0 + (double)p1 + (double)p2 + (double)p3;
    for (int off = 32; off; off >>= 1) acc += __shfl_down(acc, off, 64);
    if (lane == 0) cbsq[row] = (float)acc;
}

// ---------------- kernel 2: main VQ ----------------
// block: 256 threads (4 waves). tile: TN=64 queries x full K loop in TK=64 chunks.
// thread (tn = t&15, tk = t>>4) owns 4 n x 4 k micro-tile.
__global__ __launch_bounds__(256, 1) void vq_kernel(const float* __restrict__ x,
                                                    const float* __restrict__ cb,
                                                    const float* __restrict__ cbsq,
                                                    float* __restrict__ out) {
    __shared__ float xs[C_][TN + 4];      // xs[c][nl] = x[b][c][p0+nl]   68KB
    __shared__ float cs[C_][TK + 4];      // cs[c][kl] = cb[k0+kl][c]     68KB
    __shared__ float xsq_l[TN];
    __shared__ float red_s[16][16][4];
    __shared__ int   red_k[16][16][4];
    __shared__ int   kfin[TN];

    const int t  = threadIdx.x;
    const int tn = t & 15;
    const int tk = t >> 4;
    const int n0 = blockIdx.x * TN;
    const int b  = n0 >> 10;          // 64 | 1024 so a block never spans b
    const int p0 = n0 & 1023;

    // ---- stage x tile: 16384 elems, coalesced 64-float runs ----
    for (int i = 0; i < 64; ++i) {
        int f = t + 256 * i;
        int c = f >> 6, nl = f & 63;
        xs[c][nl] = x[(b * C_ + c) * P_ + p0 + nl];
    }
    __syncthreads();

    // ---- x_sq per row (f32 products, f64 sum, round once) ----
    if (t < TN) {
        double acc = 0.0;
        for (int c = 0; c < C_; ++c) { float v = xs[c][t]; float p = v * v; acc += (double)p; }
        xsq_l[t] = (float)acc;
    }

    float best_s[4];
    int   best_k[4];
    #pragma unroll
    for (int i = 0; i < 4; ++i) { best_s[i] = 3.0e38f; best_k[i] = 0; }

    for (int kt = 0; kt < K_ / TK; ++kt) {
        const int k0 = kt * TK;
        __syncthreads();   // protect cs (and first-iter xsq_l) before overwrite
        // stage cb chunk transposed: global coalesced over c
        for (int i = 0; i < 64; ++i) {
            int f = t + 256 * i;
            int kl = f >> 8, c = f & 255;
            cs[c][kl] = cb[(k0 + kl) * C_ + c];
        }
        __syncthreads();

        float acc[4][4] = {};
        #pragma unroll 4
        for (int c = 0; c < C_; ++c) {
            float4 xv = *reinterpret_cast<const float4*>(&xs[c][tn * 4]);
            float4 cv = *reinterpret_cast<const float4*>(&cs[c][tk * 4]);
            float xa[4] = {xv.x, xv.y, xv.z, xv.w};
            float ca[4] = {cv.x, cv.y, cv.z, cv.w};
            #pragma unroll
            for (int i = 0; i < 4; ++i)
                #pragma unroll
                for (int j = 0; j < 4; ++j)
                    acc[i][j] = fmaf(xa[i], ca[j], acc[i][j]);
        }

        const float4 cq = *reinterpret_cast<const float4*>(cbsq + k0 + tk * 4);
        const float cqa[4] = {cq.x, cq.y, cq.z, cq.w};
        #pragma unroll
        for (int i = 0; i < 4; ++i) {
            const float xq = xsq_l[tn * 4 + i];
            #pragma unroll
            for (int j = 0; j < 4; ++j) {
                // replicate reference f32 rounding: fl(fl(x_sq - 2*cross) + cb_sq)
                float s1 = xq - 2.0f * acc[i][j];
                float s2 = s1 + cqa[j];
                int   kk = k0 + tk * 4 + j;
                if (s2 < best_s[i]) { best_s[i] = s2; best_k[i] = kk; }  // ties keep lowest k
            }
        }
    }

    // ---- reduce across tk (16 partials per n) ----
    #pragma unroll
    for (int i = 0; i < 4; ++i) { red_s[tk][tn][i] = best_s[i]; red_k[tk][tn][i] = best_k[i]; }
    __syncthreads();
    if (t < TN) {
        const int tn2 = t >> 2, i = t & 3;     // nl == t
        float bs = red_s[0][tn2][i];
        int   bk = red_k[0][tn2][i];
        for (int tk2 = 1; tk2 < 16; ++tk2) {
            float s = red_s[tk2][tn2][i];
            int   k = red_k[tk2][tn2][i];
            if (s < bs || (s == bs && k < bk)) { bs = s; bk = k; }
        }
        kfin[t] = bk;
        out[QOFF + n0 + t] = (float)bk;        // indices as f32 values
    }
    __syncthreads();

    // ---- gather quantized output: out0[b][c][p0+nl] = cb[kfin[nl]][c] ----
    for (int i = 0; i < 64; ++i) {
        int f = t + 256 * i;
        int c = f >> 6, nl = f & 63;
        out[(b * C_ + c) * P_ + p0 + nl] = cb[kfin[nl] * C_ + c];
    }
}

extern "C" void kernel_launch(void* const* d_in, const int* in_sizes, int n_in,
                              void* d_out, int out_size, void* d_ws, size_t ws_size,
                              hipStream_t stream) {
    const float* x  = (const float*)d_in[0];
    const float* cb = (const float*)d_in[1];
    float* out  = (float*)d_out;
    float* cbsq = (float*)d_ws;   // 8192 floats

    hipLaunchKernelGGL(cbsq_kernel, dim3(K_ / 4), dim3(256), 0, stream, cb, cbsq);
    hipLaunchKernelGGL(vq_kernel, dim3(N_ / TN), dim3(256), 0, stream, x, cb, cbsq, out);
}

// Round 2
// 517.129 us; speedup vs baseline: 5.1593x; 5.1593x over previous
//
#include <hip/hip_runtime.h>
#include <hip/hip_bf16.h>

#define C_   256
#define P_   1024
#define N_   32768
#define K_   8192
#define QOFF 8388608   // float offset of indices in d_out
#define CAP  64
#define EPS  1e-3f

// scratch layout inside d_out's quantized region (byte offsets); all of it is
// consumed before the final gather kernel overwrites [0, 32MB).
#define XBF_OFF   0u          // ushort[32768*256]  16MB  bf16(x) row-major [n][c]
#define CBBF_OFF  16777216u   // ushort[8192*256]    4MB  bf16(cb) [k][c]
#define CAND_OFF  20971520u   // int[32768*64]       8MB  candidate k lists
#define CNT_OFF   29360128u   // int[32768]
#define GMIN_OFF  29491200u   // uint[32768] order-mapped f32 min
#define CBSQ_OFF  29622272u   // float[8192]
#define XSQ_OFF   29655040u   // float[32768]

typedef __attribute__((ext_vector_type(8))) short bf16x8;
typedef __attribute__((ext_vector_type(4))) float f32x4;

__device__ inline unsigned fkey(float f) {
    unsigned u = __float_as_uint(f);
    return (u & 0x80000000u) ? ~u : (u | 0x80000000u);
}
__device__ inline float funkey(unsigned k) {
    unsigned u = (k & 0x80000000u) ? (k ^ 0x80000000u) : ~k;
    return __uint_as_float(u);
}
__device__ inline void gload_lds16(const void* g, void* l) {
    __builtin_amdgcn_global_load_lds((const __attribute__((address_space(1))) void*)g,
                                     (__attribute__((address_space(3))) void*)l, 16, 0, 0);
}
__device__ inline unsigned short bfbits(float f) {
    __hip_bfloat16 h = __float2bfloat16(f);
    return *(unsigned short*)&h;
}

// ---------- prep_x: transpose x -> bf16 [n][c], xsq[n], init cnt/gmin ----------
__global__ __launch_bounds__(256) void prep_x(const float* __restrict__ x,
                                              char* __restrict__ outb) {
    __shared__ float xs[C_][66];
    unsigned short* xbf = (unsigned short*)(outb + XBF_OFF);
    float*    xsq  = (float*)(outb + XSQ_OFF);
    int*      cnt  = (int*)(outb + CNT_OFF);
    unsigned* gmin = (unsigned*)(outb + GMIN_OFF);
    const int t = threadIdx.x;
    const int n0 = blockIdx.x * 64;
    const int b = n0 >> 10, p0 = n0 & 1023;
    for (int i = 0; i < 64; ++i) {
        int f = t + 256 * i; int c = f >> 6, nl = f & 63;
        xs[c][nl] = x[(b * C_ + c) * P_ + p0 + nl];
    }
    __syncthreads();
    if (t < 64) {
        double acc = 0.0;
        for (int c = 0; c < C_; ++c) { float v = xs[c][t]; float pq = v * v; acc += (double)pq; }
        xsq[n0 + t] = (float)acc;
        cnt[n0 + t] = 0;
        gmin[n0 + t] = 0xFFFFFFFFu;
    }
    for (int i = 0; i < 64; ++i) {
        int f = t + 256 * i; int nl = f >> 8, c = f & 255;
        xbf[(n0 + nl) * C_ + c] = bfbits(xs[c][nl]);
    }
}

// ---------- prep_cb: cbsq (f32 squares, f64 sum, round once) + bf16 copy ----------
__global__ __launch_bounds__(256) void prep_cb(const float* __restrict__ cb,
                                               char* __restrict__ outb) {
    float* cbsq = (float*)(outb + CBSQ_OFF);
    unsigned short* cbbf = (unsigned short*)(outb + CBBF_OFF);
    const int row  = blockIdx.x * 4 + (threadIdx.x >> 6);
    const int lane = threadIdx.x & 63;
    const float4 v = *reinterpret_cast<const float4*>(cb + row * C_ + lane * 4);
    float p0 = v.x * v.x, p1 = v.y * v.y, p2 = v.z * v.z, p3 = v.w * v.w;
    double acc = (double)p0 + (double)p1 + (double)p2 + (double)p3;
    for (int off = 32; off; off >>= 1) acc += __shfl_down(acc, off, 64);
    if (lane == 0) cbsq[row] = (float)acc;
    ushort4 u = { bfbits(v.x), bfbits(v.y), bfbits(v.z), bfbits(v.w) };
    *reinterpret_cast<ushort4*>(cbbf + row * C_ + lane * 4) = u;
}

// ---------- MFMA screen: 128x128 tile, BK=64, m97 structure ----------
// COLLECT=0: half-sampled k-panels, per-row bf16-score min -> gmin (atomicMin)
// COLLECT=1: all k, collect k with score < gmin + EPS into cand lists
template <int COLLECT>
__global__ __launch_bounds__(256) void vq_mfma(char* __restrict__ outb) {
    __shared__ unsigned short tA[128 * 64];   // 16KB  x-tile   [row][c] bf16
    __shared__ unsigned short tB[128 * 64];   // 16KB  cb-tile  [row][c] bf16
    __shared__ float cbsq_l[128];
    __shared__ float th_l[128];
    const unsigned short* xbf  = (const unsigned short*)(outb + XBF_OFF);
    const unsigned short* cbbf = (const unsigned short*)(outb + CBBF_OFF);
    const float* cbsq = (const float*)(outb + CBSQ_OFF);
    unsigned* gmin = (unsigned*)(outb + GMIN_OFF);
    int* cnt  = (int*)(outb + CNT_OFF);
    int* cand = (int*)(outb + CAND_OFF);

    const int t = threadIdx.x;
    const int l = t & 63, w = t >> 6;
    const int wn = w >> 1, wk = w & 1;         // 2x2 waves over (n,k)
    const int n0 = blockIdx.x * 128;
    const int k0 = COLLECT ? blockIdx.y * 128 : blockIdx.y * 256;

    if (t < 128) {
        cbsq_l[t] = cbsq[k0 + t];
        th_l[t] = COLLECT ? (funkey(gmin[n0 + t]) + EPS) : 0.f;
    }

    f32x4 acc[4][4];
    #pragma unroll
    for (int i = 0; i < 4; ++i)
        #pragma unroll
        for (int j = 0; j < 4; ++j) acc[i][j] = (f32x4)(0.f);

    const int lr = l >> 3;           // row-within-sweep
    const int lc = (l & 7) * 8;      // c offset (ushorts)

    for (int ct = 0; ct < 4; ++ct) {
        const int c0 = ct * 64;
        #pragma unroll
        for (int s = 0; s < 4; ++s) {
            const int row = w * 8 + s * 32 + lr;
            gload_lds16(xbf  + (unsigned)(n0 + row) * C_ + c0 + lc, (char*)tA + w * 1024 + s * 4096);
            gload_lds16(cbbf + (unsigned)(k0 + row) * C_ + c0 + lc, (char*)tB + w * 1024 + s * 4096);
        }
        __syncthreads();             // drains vmcnt -> LDS tiles ready
        #pragma unroll
        for (int cs = 0; cs < 2; ++cs) {
            bf16x8 a[4], bb[4];
            const int gb = (cs * 4 + (l >> 4)) * 16;   // byte offset in 128B row
            #pragma unroll
            for (int i = 0; i < 4; ++i) {
                const int rowA = wn * 64 + i * 16 + (l & 15);
                a[i]  = *reinterpret_cast<const bf16x8*>((const char*)tA + rowA * 128 + gb);
                const int rowB = wk * 64 + i * 16 + (l & 15);
                bb[i] = *reinterpret_cast<const bf16x8*>((const char*)tB + rowB * 128 + gb);
            }
            #pragma unroll
            for (int i = 0; i < 4; ++i)
                #pragma unroll
                for (int j = 0; j < 4; ++j)
                    acc[i][j] = __builtin_amdgcn_mfma_f32_16x16x32_bf16(a[i], bb[j], acc[i][j], 0, 0, 0);
        }
        __syncthreads();             // done reading before next stage overwrite
    }

    // epilogue: score = cbsq[k] - 2*cross   (n: row=(l>>4)*4+q, k: col=l&15)
    if (COLLECT) {
        #pragma unroll
        for (int i = 0; i < 4; ++i) {
            float th[4];
            #pragma unroll
            for (int q = 0; q < 4; ++q) th[q] = th_l[wn * 64 + i * 16 + (l >> 4) * 4 + q];
            #pragma unroll
            for (int j = 0; j < 4; ++j) {
                const float cq = cbsq_l[wk * 64 + j * 16 + (l & 15)];
                const int   kg = k0 + wk * 64 + j * 16 + (l & 15);
                #pragma unroll
                for (int q = 0; q < 4; ++q) {
                    const float s = fmaf(-2.0f, acc[i][j][q], cq);
                    if (s < th[q]) {
                        const int ng = n0 + wn * 64 + i * 16 + (l >> 4) * 4 + q;
                        const int pos = atomicAdd(&cnt[ng], 1);
                        if (pos < CAP) cand[ng * CAP + pos] = kg;
                    }
                }
            }
        }
    } else {
        #pragma unroll
        for (int i = 0; i < 4; ++i) {
            float m[4] = {3e38f, 3e38f, 3e38f, 3e38f};
            #pragma unroll
            for (int j = 0; j < 4; ++j) {
                const float cq = cbsq_l[wk * 64 + j * 16 + (l & 15)];
                #pragma unroll
                for (int q = 0; q < 4; ++q)
                    m[q] = fminf(m[q], fmaf(-2.0f, acc[i][j][q], cq));
            }
            #pragma unroll
            for (int q = 0; q < 4; ++q) {
                #pragma unroll
                for (int off = 1; off < 16; off <<= 1)
                    m[q] = fminf(m[q], __shfl_xor(m[q], off, 64));
                if ((l & 15) == 0)
                    atomicMin(&gmin[n0 + wn * 64 + i * 16 + (l >> 4) * 4 + q], fkey(m[q]));
            }
        }
    }
}

// ---------- rescore: exact f32 chain (round-1 semantics) over candidates ----------
__global__ __launch_bounds__(256) void rescore(const float* __restrict__ x,
                                               const float* __restrict__ cb,
                                               float* __restrict__ outf,
                                               char* __restrict__ outb) {
    __shared__ float xrow[4][C_];
    const float* cbsq = (const float*)(outb + CBSQ_OFF);
    const float* xsq  = (const float*)(outb + XSQ_OFF);
    const int*   cnt  = (const int*)(outb + CNT_OFF);
    const int*   cand = (const int*)(outb + CAND_OFF);
    const int t = threadIdx.x, l = t & 63, w = t >> 6;
    const int n = blockIdx.x * 4 + w;
    const int b = n >> 10, p = n & 1023;
    #pragma unroll
    for (int i = 0; i < 4; ++i) {
        const int c = l + i * 64;
        xrow[w][c] = x[(b * C_ + c) * P_ + p];
    }
    __syncthreads();
    int m = cnt[n]; if (m > CAP) m = CAP;
    float s2 = 3e38f; int bk = 0x7FFFFFFF;
    if (l < m) {
        const int k = cand[n * CAP + l];
        float acc = 0.f;
        const float4* cb4 = reinterpret_cast<const float4*>(cb + k * C_);
        #pragma unroll 4
        for (int c4 = 0; c4 < 64; ++c4) {
            const float4 cv = cb4[c4];
            acc = fmaf(xrow[w][c4 * 4 + 0], cv.x, acc);
            acc = fmaf(xrow[w][c4 * 4 + 1], cv.y, acc);
            acc = fmaf(xrow[w][c4 * 4 + 2], cv.z, acc);
            acc = fmaf(xrow[w][c4 * 4 + 3], cv.w, acc);
        }
        const float s1 = xsq[n] - 2.0f * acc;   // 2*acc exact, single rounding
        s2 = s1 + cbsq[k];
        bk = k;
    }
    #pragma unroll
    for (int off = 32; off; off >>= 1) {
        const float so = __shfl_xor(s2, off, 64);
        const int   ko = __shfl_xor(bk, off, 64);
        if (so < s2 || (so == s2 && ko < bk)) { s2 = so; bk = ko; }
    }
    if (l == 0) outf[QOFF + n] = (float)bk;
}

// ---------- gather: quantized[b][c][p] = cb[idx[n]][c] ----------
__global__ __launch_bounds__(256) void gather(const float* __restrict__ cb,
                                              float* __restrict__ outf) {
    __shared__ int kf[64];
    const int t = threadIdx.x;
    const int n0 = blockIdx.x * 64;
    const int b = n0 >> 10, p0 = n0 & 1023;
    if (t < 64) kf[t] = (int)outf[QOFF + n0 + t];
    __syncthreads();
    for (int i = 0; i < 64; ++i) {
        int f = t + 256 * i; int c = f >> 6, nl = f & 63;
        outf[(b * C_ + c) * P_ + p0 + nl] = cb[kf[nl] * C_ + c];
    }
}

extern "C" void kernel_launch(void* const* d_in, const int* in_sizes, int n_in,
                              void* d_out, int out_size, void* d_ws, size_t ws_size,
                              hipStream_t stream) {
    const float* x  = (const float*)d_in[0];
    const float* cb = (const float*)d_in[1];
    float* outf = (float*)d_out;
    char*  outb = (char*)d_out;

    prep_x<<<N_ / 64, 256, 0, stream>>>(x, outb);
    prep_cb<<<K_ / 4, 256, 0, stream>>>(cb, outb);
    vq_mfma<0><<<dim3(N_ / 128, 32), 256, 0, stream>>>(outb);  // half-sampled min
    vq_mfma<1><<<dim3(N_ / 128, 64), 256, 0, stream>>>(outb);  // collect
    rescore<<<N_ / 4, 256, 0, stream>>>(x, cb, outf, outb);
    gather<<<N_ / 64, 256, 0, stream>>>(cb, outf);
}